// Round 8
// baseline (124.085 us; speedup 1.0000x reference)
//
#include <hip/hip_runtime.h>

// NCN recurrence, 2 layers. B=4, N=4096, E=128, NK=4, ce=32, CACHE=32, m=128.
// 2048 independent [32 x 32] subproblems; one single-wave block each.
// Lane (h,o) owns feats [h*16,h*16+16) of row o as 8x float2 (packed VOP3P).
//
// R8: DS-traffic restructure. R4-R7 plateau at ~31 us/layer; models point at
// the 19 ds_bpermute_b32/step (4 B/lane each, LDS pipe shared by 8 waves/CU).
// Replace with 9 denser DS insts/step:
//   - rowbuf[32] in LDS holds row j; its 2 owner lanes publish updated state
//     at end of step j-1 (4 exec-masked ds_write_b128, 2 active lanes);
//   - all lanes read xj via 4 ds_read_b128 (16 B/lane, broadcast-per-half,
//     conflict-free);
//   - sim reduction collapses: u = dot16(xi,wi) + dot16(xj,wj) makes the
//     Wj term lane-uniform per half, so sim = u + shfl_xor(u,32) -- ONE
//     cross-lane op replaces shfl + 2 dj-bpermutes.
// Weights pre-scaled by L1=log2(e); tanh via 0.1*F = 0.1 - 0.2/(exp2(arg)+1),
// arg = L1*xi + (L1*sim)*xj, unclamped (exp2 over/underflow -> exact +-1).
// Layer 0: d_in -> d_ws; layer 1: d_ws -> d_out (pure dispatches, replay-safe).

namespace {
constexpr int kB = 4;
constexpr int kN = 4096;
constexpr int kE = 128;
constexpr int kCE = 32;          // E / NK
constexpr int kH  = 16;          // feats per lane
constexpr int kQ  = kH / 2;      // float2 count
constexpr int kCache = 32;
constexpr int kM = kN / kCache;  // 128 groups per batch

typedef __attribute__((ext_vector_type(2))) float f32x2;

__device__ __forceinline__ f32x2 pk_fma(f32x2 a, f32x2 b, f32x2 c) {
    return __builtin_elementwise_fma(a, b, c);
}
}  // namespace

__global__ void __launch_bounds__(64, 2) ncn_layer_kernel(
    const float* __restrict__ x_in, const float* __restrict__ xa_in,
    const float* __restrict__ Wl,   // this layer's 256 floats
    float* __restrict__ x_out, float* __restrict__ xa_out,
    int s)                          // group stride: 0 for stage 0, 1 for stage 1
{
    const int blk = blockIdx.x;         // ((b*128 + g)*4 + n)
    const int n   = blk & 3;
    const int g   = (blk >> 2) & (kM - 1);
    const int b   = blk >> 9;
    const int t   = threadIdx.x;        // 0..63
    const int o   = t & 31;
    const int h   = t >> 5;

    // row index: ((g + o*s) % m) * CACHE + o
    const int r = (((g + o * s) & (kM - 1)) << 5) + o;
    const size_t base = ((size_t)(b * kN + r)) * kE + n * kCE + h * kH;

    constexpr float L1 = 1.4426950408889634f;   // log2(e)

    f32x2 xi[kQ], xa[kQ], wi[kQ], wj[kQ];

    {
        const float4* xi4 = reinterpret_cast<const float4*>(x_in + base);
        const float4* xa4 = reinterpret_cast<const float4*>(xa_in + base);
        const float4* wi4 = reinterpret_cast<const float4*>(Wl + n * kCE + h * kH);
        const float4* wj4 = reinterpret_cast<const float4*>(Wl + kE + n * kCE + h * kH);
#pragma unroll
        for (int q = 0; q < kQ / 2; ++q) {
            float4 v = xi4[q];
            xi[2 * q + 0] = f32x2{v.x, v.y}; xi[2 * q + 1] = f32x2{v.z, v.w};
            float4 a = xa4[q];
            xa[2 * q + 0] = f32x2{a.x, a.y}; xa[2 * q + 1] = f32x2{a.z, a.w};
            float4 u = wi4[q];   // pre-scale by L1: dots yield L1*sim directly
            wi[2 * q + 0] = f32x2{u.x * L1, u.y * L1};
            wi[2 * q + 1] = f32x2{u.z * L1, u.w * L1};
            float4 w = wj4[q];
            wj[2 * q + 0] = f32x2{w.x * L1, w.y * L1};
            wj[2 * q + 1] = f32x2{w.z * L1, w.w * L1};
        }
    }

    __shared__ float rowbuf[kCE];   // current row j (both 16-float halves)

    // publish row 0
    if (o == 0) {
        float4* w4 = reinterpret_cast<float4*>(&rowbuf[h * kH]);
#pragma unroll
        for (int q = 0; q < kQ / 2; ++q) {
            float4 v;
            v.x = xi[2 * q + 0].x; v.y = xi[2 * q + 0].y;
            v.z = xi[2 * q + 1].x; v.w = xi[2 * q + 1].y;
            w4[q] = v;
        }
    }
    __syncthreads();

#pragma unroll 4
    for (int j = 0; j < kCache; ++j) {
        // (1) fetch row j: 4x ds_read_b128, broadcast within each half
        f32x2 xj[kQ];
        {
            const float4* r4 = reinterpret_cast<const float4*>(&rowbuf[h * kH]);
#pragma unroll
            for (int q = 0; q < kQ / 2; ++q) {
                float4 v = r4[q];
                xj[2 * q + 0] = f32x2{v.x, v.y};
                xj[2 * q + 1] = f32x2{v.z, v.w};
            }
        }

        // (2) u = dot16(xi,wi) + dot16(xj,wj)  (Wj term lane-uniform per half)
        f32x2 a01 = xi[0] * wi[0];
        f32x2 a23 = xi[1] * wi[1];
        f32x2 b01 = xj[0] * wj[0];
        f32x2 b23 = xj[1] * wj[1];
#pragma unroll
        for (int q = 2; q < kQ; q += 2) {
            a01 = pk_fma(xi[q + 0], wi[q + 0], a01);
            a23 = pk_fma(xi[q + 1], wi[q + 1], a23);
            b01 = pk_fma(xj[q + 0], wj[q + 0], b01);
            b23 = pk_fma(xj[q + 1], wj[q + 1], b23);
        }
        f32x2 uv = (a01 + a23) + (b01 + b23);
        float u  = uv.x + uv.y;

        // (3) one cross-lane op: sum the two halves
        const float sim = u + __shfl_xor(u, 32, 64);   // = L1 * sim_true
        const f32x2 sv  = {sim, sim};
        const f32x2 l12 = {L1, L1};
        const f32x2 one = {1.0f, 1.0f};
        const f32x2 m02 = {-0.2f, -0.2f};
        const f32x2 c9  = {0.9f, 0.9f};
        const f32x2 c01 = {0.1f, 0.1f};

#pragma unroll
        for (int q = 0; q < kQ; ++q) {
            f32x2 arg = pk_fma(xj[q], sv, xi[q] * l12);  // 2*L1*T
            f32x2 t2;
            t2.x = __builtin_amdgcn_exp2f(arg.x);
            t2.y = __builtin_amdgcn_exp2f(arg.y);
            f32x2 den = t2 + one;
            f32x2 rc;
            rc.x = __builtin_amdgcn_rcpf(den.x);
            rc.y = __builtin_amdgcn_rcpf(den.y);
            // xa' = 0.9*xa + 0.1*tanh = (0.9*xa + 0.1) - 0.2*rc
            xa[q] = pk_fma(m02, rc, pk_fma(c9, xa[q], c01));
            // xi' = 0.9*xi + 0.1*xa'
            xi[q] = pk_fma(c01, xa[q], xi[q] * c9);
        }

        // (4) row j+1 owners publish updated state (2 active lanes)
        if (o == ((j + 1) & 31)) {
            float4* w4 = reinterpret_cast<float4*>(&rowbuf[h * kH]);
#pragma unroll
            for (int q = 0; q < kQ / 2; ++q) {
                float4 v;
                v.x = xi[2 * q + 0].x; v.y = xi[2 * q + 0].y;
                v.z = xi[2 * q + 1].x; v.w = xi[2 * q + 1].y;
                w4[q] = v;
            }
        }
        __syncthreads();   // single wave: waitcnt drain + trivial barrier
    }

    {
        float4* xo4 = reinterpret_cast<float4*>(x_out + base);
        float4* ao4 = reinterpret_cast<float4*>(xa_out + base);
#pragma unroll
        for (int q = 0; q < kQ / 2; ++q) {
            float4 v;
            v.x = xi[2 * q + 0].x; v.y = xi[2 * q + 0].y;
            v.z = xi[2 * q + 1].x; v.w = xi[2 * q + 1].y;
            xo4[q] = v;
            float4 a;
            a.x = xa[2 * q + 0].x; a.y = xa[2 * q + 0].y;
            a.z = xa[2 * q + 1].x; a.w = xa[2 * q + 1].y;
            ao4[q] = a;
        }
    }
}

extern "C" void kernel_launch(void* const* d_in, const int* in_sizes, int n_in,
                              void* d_out, int out_size, void* d_ws, size_t ws_size,
                              hipStream_t stream) {
    const float* x  = (const float*)d_in[0];   // [B, N, E] fp32
    const float* xa = (const float*)d_in[1];   // [B, N, E] fp32
    const float* W  = (const float*)d_in[2];   // [2, 256] fp32

    const size_t plane = (size_t)kB * kN * kE;   // 2,097,152 floats

    float* x_mid  = (float*)d_ws;                // layer-0 outputs in workspace
    float* xa_mid = x_mid + plane;               // (32 MB total)

    float* x_out  = (float*)d_out;               // final outputs
    float* xa_out = x_out + plane;

    const dim3 grid(kB * kM * 4);   // 2048 single-wave blocks
    const dim3 block(64);

    // Layer 0 (stage 0, s = 0): d_in -> ws       (pure, idempotent)
    ncn_layer_kernel<<<grid, block, 0, stream>>>(x, xa, W, x_mid, xa_mid, 0);
    // Layer 1 (stage 1, s = 1): ws -> d_out      (pure, idempotent)
    ncn_layer_kernel<<<grid, block, 0, stream>>>(x_mid, xa_mid, W + 2 * kE,
                                                 x_out, xa_out, 1);
}

// Round 9
// 120.253 us; speedup vs baseline: 1.0319x; 1.0319x over previous
//
#include <hip/hip_runtime.h>

// NCN recurrence, 2 layers. B=4, N=4096, E=128, NK=4, ce=32, CACHE=32, m=128.
// 2048 independent [32 rows x 32 feats] subproblems.
//
// R9: OCCUPANCY. R4-R8 plateau at ~32 us/layer with 2 waves/SIMD; issue
// audit says ~550 cyc/step/wave + ~700 cyc serial chain -> bubble-bound.
// Split each subproblem across TWO waves (block=128): 4096 waves = 4/SIMD.
//   thread: w = t>>6, l = t&63; or = l>>2 (row-in-half), f = l&3 (feat grp);
//   owns feats [f*8, f*8+8) of row (w*16 + or). Per-wave issue work halves;
//   bubble coverage doubles.
// Row-j broadcast: double-buffered LDS rowbuf[2][32]; row j+1's 4 owner
// threads publish after update (2x ds_write_b128); readers fetch 8 floats
// (2x ds_read_b128, offsets 0/8/16/24 floats -> conflict-free). One block
// barrier per step (hidden at 4 waves/SIMD).
// sim: u = p(xi.Wi) + p(xj.Wj) over own 8 feats; sim = reduce over f-group
// via shfl_xor(1) + shfl_xor(2). Weights pre-scaled by L1=log2(e);
// tanh via 0.1*F = 0.1 - 0.2/(exp2(arg)+1), arg = L1*xi + (L1*sim)*xj,
// unclamped (exp2 over/underflow -> exact +-1 limit).
// Layer 0: d_in -> d_ws; layer 1: d_ws -> d_out (pure dispatches, replay-safe).

namespace {
constexpr int kB = 4;
constexpr int kN = 4096;
constexpr int kE = 128;
constexpr int kCE = 32;          // E / NK
constexpr int kF  = 8;           // feats per thread
constexpr int kQ  = kF / 2;      // float2 count per thread
constexpr int kCache = 32;
constexpr int kM = kN / kCache;  // 128 groups per batch

typedef __attribute__((ext_vector_type(2))) float f32x2;

__device__ __forceinline__ f32x2 pk_fma(f32x2 a, f32x2 b, f32x2 c) {
    return __builtin_elementwise_fma(a, b, c);
}
}  // namespace

__global__ void __launch_bounds__(128) ncn_layer_kernel(
    const float* __restrict__ x_in, const float* __restrict__ xa_in,
    const float* __restrict__ Wl,   // this layer's 256 floats
    float* __restrict__ x_out, float* __restrict__ xa_out,
    int s)                          // group stride: 0 for stage 0, 1 for stage 1
{
    const int blk = blockIdx.x;         // ((b*128 + g)*4 + n)
    const int n   = blk & 3;
    const int g   = (blk >> 2) & (kM - 1);
    const int b   = blk >> 9;
    const int t   = threadIdx.x;        // 0..127
    const int w   = t >> 6;             // wave: rows [w*16, w*16+16)
    const int l   = t & 63;
    const int orr = l >> 2;             // row within half
    const int f   = l & 3;              // feat group: feats [f*8, f*8+8)
    const int row = w * 16 + orr;       // row in group, 0..31

    // global row: ((g + row*s) % m) * CACHE + row
    const int r = (((g + row * s) & (kM - 1)) << 5) + row;
    const size_t base = ((size_t)(b * kN + r)) * kE + n * kCE + f * kF;

    constexpr float L1 = 1.4426950408889634f;   // log2(e)

    f32x2 xi[kQ], xa[kQ], wi[kQ], wj[kQ];

    {
        const float4* xi4 = reinterpret_cast<const float4*>(x_in + base);
        const float4* xa4 = reinterpret_cast<const float4*>(xa_in + base);
        const float4* wi4 = reinterpret_cast<const float4*>(Wl + n * kCE + f * kF);
        const float4* wj4 = reinterpret_cast<const float4*>(Wl + kE + n * kCE + f * kF);
#pragma unroll
        for (int q = 0; q < kQ / 2; ++q) {
            float4 v = xi4[q];
            xi[2 * q + 0] = f32x2{v.x, v.y}; xi[2 * q + 1] = f32x2{v.z, v.w};
            float4 a = xa4[q];
            xa[2 * q + 0] = f32x2{a.x, a.y}; xa[2 * q + 1] = f32x2{a.z, a.w};
            float4 u = wi4[q];   // pre-scale by L1: dots yield L1*sim directly
            wi[2 * q + 0] = f32x2{u.x * L1, u.y * L1};
            wi[2 * q + 1] = f32x2{u.z * L1, u.w * L1};
            float4 ww = wj4[q];
            wj[2 * q + 0] = f32x2{ww.x * L1, ww.y * L1};
            wj[2 * q + 1] = f32x2{ww.z * L1, ww.w * L1};
        }
    }

    __shared__ float rowbuf[2][kCE];    // double-buffered row-j broadcast

    // publish row 0 into buffer 0 (owners: w==0, orr==0; 4 threads)
    if (t < 4) {
        float4* w4 = reinterpret_cast<float4*>(&rowbuf[0][f * kF]);
#pragma unroll
        for (int q = 0; q < kQ / 2; ++q) {
            float4 v;
            v.x = xi[2 * q + 0].x; v.y = xi[2 * q + 0].y;
            v.z = xi[2 * q + 1].x; v.w = xi[2 * q + 1].y;
            w4[q] = v;
        }
    }
    __syncthreads();

#pragma unroll 4
    for (int j = 0; j < kCache; ++j) {
        const int p = j & 1;

        // (1) fetch row j's 8-feat slice: 2x ds_read_b128 (broadcast groups)
        f32x2 xj[kQ];
        {
            const float4* r4 = reinterpret_cast<const float4*>(&rowbuf[p][f * kF]);
#pragma unroll
            for (int q = 0; q < kQ / 2; ++q) {
                float4 v = r4[q];
                xj[2 * q + 0] = f32x2{v.x, v.y};
                xj[2 * q + 1] = f32x2{v.z, v.w};
            }
        }

        // (2) u = p(xi.Wi) + p(xj.Wj) over own 8 feats
        f32x2 a01 = xi[0] * wi[0];
        f32x2 a23 = xi[1] * wi[1];
        f32x2 b01 = xj[0] * wj[0];
        f32x2 b23 = xj[1] * wj[1];
        a01 = pk_fma(xi[2], wi[2], a01);
        a23 = pk_fma(xi[3], wi[3], a23);
        b01 = pk_fma(xj[2], wj[2], b01);
        b23 = pk_fma(xj[3], wj[3], b23);
        f32x2 uv = (a01 + a23) + (b01 + b23);
        float u  = uv.x + uv.y;

        // (3) reduce over the 4-lane f-group -> sim (= L1 * sim_true)
        u += __shfl_xor(u, 1, 64);
        u += __shfl_xor(u, 2, 64);
        const float sim = u;
        const f32x2 sv  = {sim, sim};
        const f32x2 l12 = {L1, L1};
        const f32x2 one = {1.0f, 1.0f};
        const f32x2 m02 = {-0.2f, -0.2f};
        const f32x2 c9  = {0.9f, 0.9f};
        const f32x2 c01 = {0.1f, 0.1f};

#pragma unroll
        for (int q = 0; q < kQ; ++q) {
            f32x2 arg = pk_fma(xj[q], sv, xi[q] * l12);  // 2*L1*T
            f32x2 t2;
            t2.x = __builtin_amdgcn_exp2f(arg.x);
            t2.y = __builtin_amdgcn_exp2f(arg.y);
            f32x2 den = t2 + one;
            f32x2 rc;
            rc.x = __builtin_amdgcn_rcpf(den.x);
            rc.y = __builtin_amdgcn_rcpf(den.y);
            // xa' = 0.9*xa + 0.1*tanh = (0.9*xa + 0.1) - 0.2*rc
            xa[q] = pk_fma(m02, rc, pk_fma(c9, xa[q], c01));
            // xi' = 0.9*xi + 0.1*xa'
            xi[q] = pk_fma(c01, xa[q], xi[q] * c9);
        }

        // (4) row j+1's owners publish updated state into the other buffer
        const int nj = (j + 1) & 31;
        if (row == nj) {
            float4* w4 = reinterpret_cast<float4*>(&rowbuf[p ^ 1][f * kF]);
#pragma unroll
            for (int q = 0; q < kQ / 2; ++q) {
                float4 v;
                v.x = xi[2 * q + 0].x; v.y = xi[2 * q + 0].y;
                v.z = xi[2 * q + 1].x; v.w = xi[2 * q + 1].y;
                w4[q] = v;
            }
        }
        __syncthreads();
    }

    {
        float4* xo4 = reinterpret_cast<float4*>(x_out + base);
        float4* ao4 = reinterpret_cast<float4*>(xa_out + base);
#pragma unroll
        for (int q = 0; q < kQ / 2; ++q) {
            float4 v;
            v.x = xi[2 * q + 0].x; v.y = xi[2 * q + 0].y;
            v.z = xi[2 * q + 1].x; v.w = xi[2 * q + 1].y;
            xo4[q] = v;
            float4 a;
            a.x = xa[2 * q + 0].x; a.y = xa[2 * q + 0].y;
            a.z = xa[2 * q + 1].x; a.w = xa[2 * q + 1].y;
            ao4[q] = a;
        }
    }
}

extern "C" void kernel_launch(void* const* d_in, const int* in_sizes, int n_in,
                              void* d_out, int out_size, void* d_ws, size_t ws_size,
                              hipStream_t stream) {
    const float* x  = (const float*)d_in[0];   // [B, N, E] fp32
    const float* xa = (const float*)d_in[1];   // [B, N, E] fp32
    const float* W  = (const float*)d_in[2];   // [2, 256] fp32

    const size_t plane = (size_t)kB * kN * kE;   // 2,097,152 floats

    float* x_mid  = (float*)d_ws;                // layer-0 outputs in workspace
    float* xa_mid = x_mid + plane;               // (32 MB total)

    float* x_out  = (float*)d_out;               // final outputs
    float* xa_out = x_out + plane;

    const dim3 grid(kB * kM * 4);   // 2048 blocks x 2 waves = 4096 waves
    const dim3 block(128);

    // Layer 0 (stage 0, s = 0): d_in -> ws       (pure, idempotent)
    ncn_layer_kernel<<<grid, block, 0, stream>>>(x, xa, W, x_mid, xa_mid, 0);
    // Layer 1 (stage 1, s = 1): ws -> d_out      (pure, idempotent)
    ncn_layer_kernel<<<grid, block, 0, stream>>>(x_mid, xa_mid, W + 2 * kE,
                                                 x_out, xa_out, 1);
}